// Round 1
// baseline (968.307 us; speedup 1.0000x reference)
//
#include <hip/hip_runtime.h>
#include <stdint.h>

typedef __attribute__((ext_vector_type(8))) short bf16x8;
typedef __attribute__((ext_vector_type(4))) short bf16x4;
typedef __attribute__((ext_vector_type(4))) float f32x4;

#define DEV static __device__ __forceinline__

DEV float bf2f(short u) {
    union { float f; uint32_t i; } v;
    v.i = ((uint32_t)(uint16_t)u) << 16;
    return v.f;
}
DEV short f2bf(float f) {
    union { float f; uint32_t i; } v; v.f = f;
    uint32_t r = v.i + 0x7fff + ((v.i >> 16) & 1);
    return (short)(r >> 16);
}

DEV void gload_lds16(const void* g, void* l) {
    __builtin_amdgcn_global_load_lds(
        (__attribute__((address_space(1))) void*)(void*)g,
        (__attribute__((address_space(3))) void*)l,
        16, 0, 0);
}

// ---------------- f32 -> bf16 conversion ----------------
__global__ __launch_bounds__(256) void cvt_kernel(const float* __restrict__ in,
                                                  ushort* __restrict__ out, int n4) {
    int idx = blockIdx.x * 256 + threadIdx.x;
    int stride = gridDim.x * 256;
    for (int i = idx; i < n4; i += stride) {
        float4 v = ((const float4*)in)[i];
        bf16x4 o;
        o.x = f2bf(v.x); o.y = f2bf(v.y); o.z = f2bf(v.z); o.w = f2bf(v.w);
        ((bf16x4*)out)[i] = o;
    }
}

// ---------------- GEMM: C[m,n] = epilogue(sum_k A[m,k]*Bw[n,k] + bias[n]) ----
// A: [M,K] bf16 row-major. Bw: [N,K] bf16 row-major (torch Linear layout).
// MODE 0: Cb = bf16(relu(acc+bias))
// MODE 1: Cb = bf16(acc+bias)
// MODE 2: Cf (+)= gate[m,expert] * (acc+bias)   (init? = : +=)
template<int MODE>
__global__ __launch_bounds__(256) void gemm_bt(
    const ushort* __restrict__ A,
    const ushort* __restrict__ Bw,
    const float* __restrict__ bias,
    ushort* __restrict__ Cb,
    float*  __restrict__ Cf,
    const float* __restrict__ gate,
    int M, int N, int K, int expert, int init)
{
    __shared__ ushort lA[128 * 64];
    __shared__ ushort lB[128 * 64];

    const int tid  = threadIdx.x;
    const int lane = tid & 63;
    const int wv   = tid >> 6;        // 0..3
    const int wr   = wv >> 1;         // wave row (0..1), 64 rows each
    const int wc   = wv & 1;          // wave col (0..1), 64 cols each
    const int m0   = blockIdx.x * 128;
    const int n0   = blockIdx.y * 128;

    const int srow = lane >> 3;        // 0..7
    const int scol = (lane & 7) * 8;   // 0,8,..,56
    const int fr   = lane & 15;
    const int fk   = (lane >> 4) * 8;

    f32x4 zero4 = {0.f, 0.f, 0.f, 0.f};
    f32x4 acc[4][4];
#pragma unroll
    for (int i = 0; i < 4; i++)
#pragma unroll
        for (int j = 0; j < 4; j++) acc[i][j] = zero4;

    for (int kt = 0; kt < K; kt += 64) {
        __syncthreads();   // previous tile fully consumed
#pragma unroll
        for (int i = 0; i < 4; i++) {
            const int chunk = wv * 4 + i;           // 0..15 (wave-uniform)
            const int row   = chunk * 8 + srow;     // 0..127
            gload_lds16(A  + (size_t)(m0 + row) * K + kt + scol, &lA[chunk * 512]);
            gload_lds16(Bw + (size_t)(n0 + row) * K + kt + scol, &lB[chunk * 512]);
        }
        __syncthreads();   // staged data visible (vmcnt drained by barrier)

#pragma unroll
        for (int ks = 0; ks < 2; ks++) {
            bf16x8 aF[4], bF[4];
#pragma unroll
            for (int i = 0; i < 4; i++)
                aF[i] = *(const bf16x8*)&lA[(wr * 64 + i * 16 + fr) * 64 + ks * 32 + fk];
#pragma unroll
            for (int j = 0; j < 4; j++)
                bF[j] = *(const bf16x8*)&lB[(wc * 64 + j * 16 + fr) * 64 + ks * 32 + fk];
#pragma unroll
            for (int i = 0; i < 4; i++)
#pragma unroll
                for (int j = 0; j < 4; j++)
                    acc[i][j] = __builtin_amdgcn_mfma_f32_16x16x32_bf16(
                        aF[i], bF[j], acc[i][j], 0, 0, 0);
        }
    }

    // Epilogue. C/D layout (m89-verified): col = lane&15, row = (lane>>4)*4 + q
    const int cr = (lane >> 4) * 4;
    const int cc = lane & 15;
#pragma unroll
    for (int i = 0; i < 4; i++) {
#pragma unroll
        for (int j = 0; j < 4; j++) {
            const int col = n0 + wc * 64 + j * 16 + cc;
            const float bv = bias[col];
#pragma unroll
            for (int q = 0; q < 4; q++) {
                const int row = m0 + wr * 64 + i * 16 + cr + q;
                float v = acc[i][j][q] + bv;
                if (MODE == 0) {
                    v = v > 0.f ? v : 0.f;
                    Cb[(size_t)row * N + col] = (ushort)f2bf(v);
                } else if (MODE == 1) {
                    Cb[(size_t)row * N + col] = (ushort)f2bf(v);
                } else {
                    const float g = gate[(size_t)row * 8 + expert];
                    const size_t idx = (size_t)row * N + col;
                    const float o = g * v;
                    if (init) Cf[idx] = o;
                    else      Cf[idx] += o;
                }
            }
        }
    }
}

// ---------------- LayerNorm + relu + residual (in place on z) ----------------
// z[r,:]  <-  bf16( relu((z-mu)*rsqrt(var+eps)*g + b) + h[r,:] )
__global__ __launch_bounds__(256) void ln_kernel(
    ushort* __restrict__ z, const ushort* __restrict__ h,
    const float* __restrict__ g, const float* __restrict__ b, int H)
{
    const int r = blockIdx.x;
    const int t = threadIdx.x;
    const size_t base = (size_t)r * H + t * 4;

    bf16x4 zv = *(const bf16x4*)&z[base];
    float zf[4];
#pragma unroll
    for (int j = 0; j < 4; j++) zf[j] = bf2f(zv[j]);

    float s  = zf[0] + zf[1] + zf[2] + zf[3];
    float s2 = zf[0]*zf[0] + zf[1]*zf[1] + zf[2]*zf[2] + zf[3]*zf[3];
#pragma unroll
    for (int off = 32; off; off >>= 1) {
        s  += __shfl_xor(s, off);
        s2 += __shfl_xor(s2, off);
    }
    __shared__ float red[8];
    const int wv = t >> 6, lane = t & 63;
    if (lane == 0) { red[wv] = s; red[4 + wv] = s2; }
    __syncthreads();
    s  = red[0] + red[1] + red[2] + red[3];
    s2 = red[4] + red[5] + red[6] + red[7];

    const float mu  = s / (float)H;
    const float var = s2 / (float)H - mu * mu;
    const float rs  = rsqrtf(var + 1e-5f);

    bf16x4 hv = *(const bf16x4*)&h[base];
    bf16x4 o;
#pragma unroll
    for (int j = 0; j < 4; j++) {
        float gn = (zf[j] - mu) * rs * g[t * 4 + j] + b[t * 4 + j];
        gn = gn > 0.f ? gn : 0.f;
        o[j] = f2bf(gn + bf2f(hv[j]));
    }
    *(bf16x4*)&z[base] = o;
}

// ---------------- gate: logits = gh @ Wg2^T + bg2 ; softmax over 8 ----------
__global__ __launch_bounds__(256) void gate2_kernel(
    const ushort* __restrict__ gh,   // [B,256] bf16
    const float* __restrict__ Wg2,   // [8,256]
    const float* __restrict__ bg2,   // [8]
    float* __restrict__ gate)        // [B,8]
{
    const int wv = threadIdx.x >> 6, lane = threadIdx.x & 63;
    const int r = blockIdx.x * 4 + wv;

    bf16x4 v = *(const bf16x4*)&gh[(size_t)r * 256 + lane * 4];
    float gf[4];
#pragma unroll
    for (int j = 0; j < 4; j++) gf[j] = bf2f(v[j]);

    float lg[8];
#pragma unroll
    for (int e = 0; e < 8; e++) {
        const float* w = Wg2 + e * 256 + lane * 4;
        float p = gf[0]*w[0] + gf[1]*w[1] + gf[2]*w[2] + gf[3]*w[3];
#pragma unroll
        for (int off = 32; off; off >>= 1) p += __shfl_xor(p, off);
        lg[e] = p + bg2[e];
    }
    float mx = lg[0];
#pragma unroll
    for (int e = 1; e < 8; e++) mx = fmaxf(mx, lg[e]);
    float ex[8], ssum = 0.f;
#pragma unroll
    for (int e = 0; e < 8; e++) { ex[e] = expf(lg[e] - mx); ssum += ex[e]; }
    const float inv = 1.f / ssum;
    float myex = 0.f;
#pragma unroll
    for (int e = 0; e < 8; e++) myex = (lane == e) ? ex[e] : myex;
    if (lane < 8) gate[(size_t)r * 8 + lane] = myex * inv;
}

// ---------------- host ----------------
extern "C" void kernel_launch(void* const* d_in, const int* in_sizes, int n_in,
                              void* d_out, int out_size, void* d_ws, size_t ws_size,
                              hipStream_t stream)
{
    const float* x   = (const float*)d_in[0];
    const float* W0  = (const float*)d_in[1];
    const float* b0  = (const float*)d_in[2];
    const float* W1  = (const float*)d_in[3];
    const float* b1  = (const float*)d_in[4];
    const float* lng = (const float*)d_in[5];
    const float* lnb = (const float*)d_in[6];
    const float* W2  = (const float*)d_in[7];
    const float* b2  = (const float*)d_in[8];
    const float* Wg1 = (const float*)d_in[9];
    const float* bg1 = (const float*)d_in[10];
    // d_in[11] = Wg2, d_in[12] = bg2
    const float* Wg2 = (const float*)d_in[11];
    const float* bg2 = (const float*)d_in[12];
    float* out = (float*)d_out;

    const int B = 8192, D = 1024, H = 1024, E = 8, G = 256;

    char* ws = (char*)d_ws;
    ushort* x_bf  = (ushort*)ws;  ws += (size_t)B * D * 2;
    ushort* w0_bf = (ushort*)ws;  ws += (size_t)E * H * D * 2;
    ushort* w1_bf = (ushort*)ws;  ws += (size_t)E * H * H * 2;
    ushort* w2_bf = (ushort*)ws;  ws += (size_t)E * D * H * 2;
    ushort* wg1bf = (ushort*)ws;  ws += (size_t)G * D * 2;
    ushort* gh_bf = (ushort*)ws;  ws += (size_t)B * G * 2;
    float*  gatep = (float*)ws;   ws += (size_t)B * E * 4;
    ushort* h_e   = (ushort*)ws;  ws += (size_t)B * H * 2;
    ushort* z_e   = (ushort*)ws;  ws += (size_t)B * H * 2;

    auto cvt = [&](const float* src, ushort* dst, size_t n) {
        int n4 = (int)(n / 4);
        int blocks = (n4 + 255) / 256;
        if (blocks > 2048) blocks = 2048;
        cvt_kernel<<<dim3(blocks), dim3(256), 0, stream>>>(src, dst, n4);
    };
    cvt(x,   x_bf,  (size_t)B * D);
    cvt(W0,  w0_bf, (size_t)E * H * D);
    cvt(W1,  w1_bf, (size_t)E * H * H);
    cvt(W2,  w2_bf, (size_t)E * D * H);
    cvt(Wg1, wg1bf, (size_t)G * D);

    // gate hidden: [B,G] = relu(x @ Wg1^T + bg1)
    gemm_bt<0><<<dim3(B / 128, G / 128), dim3(256), 0, stream>>>(
        x_bf, wg1bf, bg1, gh_bf, nullptr, nullptr, B, G, D, 0, 0);
    // gate softmax over experts
    gate2_kernel<<<dim3(B / 4), dim3(256), 0, stream>>>(gh_bf, Wg2, bg2, gatep);

    for (int e = 0; e < E; e++) {
        // layer0: h = relu(x @ W0[e]^T + b0[e])
        gemm_bt<0><<<dim3(B / 128, H / 128), dim3(256), 0, stream>>>(
            x_bf, w0_bf + (size_t)e * H * D, b0 + (size_t)e * H,
            h_e, nullptr, nullptr, B, H, D, 0, 0);
        // layer1: z = h @ W1[e]^T + b1[e]
        gemm_bt<1><<<dim3(B / 128, H / 128), dim3(256), 0, stream>>>(
            h_e, w1_bf + (size_t)e * H * H, b1 + (size_t)e * H,
            z_e, nullptr, nullptr, B, H, H, 0, 0);
        // LN -> relu -> +h   (in place: z_e becomes hp)
        ln_kernel<<<dim3(B), dim3(256), 0, stream>>>(
            z_e, h_e, lng + (size_t)e * H, lnb + (size_t)e * H, H);
        // layer2 + gated combine into out
        gemm_bt<2><<<dim3(B / 128, D / 128), dim3(256), 0, stream>>>(
            z_e, w2_bf + (size_t)e * D * H, b2 + (size_t)e * D,
            nullptr, out, gatep, B, D, H, e, (e == 0) ? 1 : 0);
    }
}

// Round 2
// 785.607 us; speedup vs baseline: 1.2326x; 1.2326x over previous
//
#include <hip/hip_runtime.h>
#include <stdint.h>

typedef __attribute__((ext_vector_type(8))) short bf16x8;
typedef __attribute__((ext_vector_type(4))) short bf16x4;
typedef __attribute__((ext_vector_type(4))) float f32x4;

#define DEV static __device__ __forceinline__

DEV float bf2f(short u) {
    union { float f; uint32_t i; } v;
    v.i = ((uint32_t)(uint16_t)u) << 16;
    return v.f;
}
DEV short f2bf(float f) {
    union { float f; uint32_t i; } v; v.f = f;
    uint32_t r = v.i + 0x7fff + ((v.i >> 16) & 1);
    return (short)(r >> 16);
}

DEV void gload_lds16(const void* g, void* l) {
    __builtin_amdgcn_global_load_lds(
        (__attribute__((address_space(1))) void*)(void*)g,
        (__attribute__((address_space(3))) void*)l,
        16, 0, 0);
}

// ---------------- f32 -> bf16 conversion ----------------
__global__ __launch_bounds__(256) void cvt_kernel(const float* __restrict__ in,
                                                  ushort* __restrict__ out, int n4) {
    int idx = blockIdx.x * 256 + threadIdx.x;
    int stride = gridDim.x * 256;
    for (int i = idx; i < n4; i += stride) {
        float4 v = ((const float4*)in)[i];
        bf16x4 o;
        o.x = f2bf(v.x); o.y = f2bf(v.y); o.z = f2bf(v.z); o.w = f2bf(v.w);
        ((bf16x4*)out)[i] = o;
    }
}

// ---------------- GEMM: C[m,n] = epilogue(sum_k A[m,k]*Bw[n,k] + bias[n]) ----
// Batched over blockIdx.z (experts). A: [M,K] bf16 rm. Bw: [N,K] bf16 rm.
// MODE 0: Cb = bf16(relu(acc+bias));  MODE 1: Cb = bf16(acc+bias)
template<int MODE>
__global__ __launch_bounds__(256) void gemm_bt(
    const ushort* __restrict__ A,
    const ushort* __restrict__ Bw,
    const float* __restrict__ bias,
    ushort* __restrict__ Cb,
    int M, int N, int K,
    long strideA, long strideB, long strideBias, long strideC)
{
    __shared__ ushort lA[128 * 64];
    __shared__ ushort lB[128 * 64];

    const int z = blockIdx.z;
    const ushort* Az = A + (size_t)z * strideA;
    const ushort* Bz = Bw + (size_t)z * strideB;
    const float*  bz = bias + (size_t)z * strideBias;
    ushort*       Cz = Cb + (size_t)z * strideC;

    const int tid  = threadIdx.x;
    const int lane = tid & 63;
    const int wv   = tid >> 6;        // 0..3
    const int wr   = wv >> 1;         // wave row (0..1), 64 rows each
    const int wc   = wv & 1;          // wave col (0..1), 64 cols each
    const int m0   = blockIdx.x * 128;
    const int n0   = blockIdx.y * 128;

    const int srow = lane >> 3;        // 0..7
    const int scol = (lane & 7) * 8;   // 0,8,..,56
    const int fr   = lane & 15;
    const int fk   = (lane >> 4) * 8;

    f32x4 zero4 = {0.f, 0.f, 0.f, 0.f};
    f32x4 acc[4][4];
#pragma unroll
    for (int i = 0; i < 4; i++)
#pragma unroll
        for (int j = 0; j < 4; j++) acc[i][j] = zero4;

    for (int kt = 0; kt < K; kt += 64) {
        __syncthreads();   // previous tile fully consumed
#pragma unroll
        for (int i = 0; i < 4; i++) {
            const int chunk = wv * 4 + i;           // 0..15 (wave-uniform)
            const int row   = chunk * 8 + srow;     // 0..127
            gload_lds16(Az + (size_t)(m0 + row) * K + kt + scol, &lA[chunk * 512]);
            gload_lds16(Bz + (size_t)(n0 + row) * K + kt + scol, &lB[chunk * 512]);
        }
        __syncthreads();   // staged data visible

#pragma unroll
        for (int ks = 0; ks < 2; ks++) {
            bf16x8 aF[4], bF[4];
#pragma unroll
            for (int i = 0; i < 4; i++)
                aF[i] = *(const bf16x8*)&lA[(wr * 64 + i * 16 + fr) * 64 + ks * 32 + fk];
#pragma unroll
            for (int j = 0; j < 4; j++)
                bF[j] = *(const bf16x8*)&lB[(wc * 64 + j * 16 + fr) * 64 + ks * 32 + fk];
#pragma unroll
            for (int i = 0; i < 4; i++)
#pragma unroll
                for (int j = 0; j < 4; j++)
                    acc[i][j] = __builtin_amdgcn_mfma_f32_16x16x32_bf16(
                        aF[i], bF[j], acc[i][j], 0, 0, 0);
        }
    }

    // Epilogue. C/D layout (m89-verified): col = lane&15, row = (lane>>4)*4 + q
    const int cr = (lane >> 4) * 4;
    const int cc = lane & 15;
#pragma unroll
    for (int i = 0; i < 4; i++) {
#pragma unroll
        for (int j = 0; j < 4; j++) {
            const int col = n0 + wc * 64 + j * 16 + cc;
            const float bv = bz[col];
#pragma unroll
            for (int q = 0; q < 4; q++) {
                const int row = m0 + wr * 64 + i * 16 + cr + q;
                float v = acc[i][j][q] + bv;
                if (MODE == 0) v = v > 0.f ? v : 0.f;
                Cz[(size_t)row * N + col] = (ushort)f2bf(v);
            }
        }
    }
}

// ---------------- LayerNorm + relu + residual (in place on z) ----------------
// z[e,r,:] <- bf16( relu(LN(z)*g + b) + h[e,r,:] ),  e = blockIdx.y (local)
__global__ __launch_bounds__(256) void ln_kernel(
    ushort* __restrict__ z, const ushort* __restrict__ h,
    const float* __restrict__ g, const float* __restrict__ b, int B, int H)
{
    const int r = blockIdx.x;
    const int e = blockIdx.y;
    const int t = threadIdx.x;
    const size_t base = ((size_t)e * B + r) * H + t * 4;
    const float* ge = g + (size_t)e * H;
    const float* be = b + (size_t)e * H;

    bf16x4 zv = *(const bf16x4*)&z[base];
    float zf[4];
#pragma unroll
    for (int j = 0; j < 4; j++) zf[j] = bf2f(zv[j]);

    float s  = zf[0] + zf[1] + zf[2] + zf[3];
    float s2 = zf[0]*zf[0] + zf[1]*zf[1] + zf[2]*zf[2] + zf[3]*zf[3];
#pragma unroll
    for (int off = 32; off; off >>= 1) {
        s  += __shfl_xor(s, off);
        s2 += __shfl_xor(s2, off);
    }
    __shared__ float red[8];
    const int wv = t >> 6, lane = t & 63;
    if (lane == 0) { red[wv] = s; red[4 + wv] = s2; }
    __syncthreads();
    s  = red[0] + red[1] + red[2] + red[3];
    s2 = red[4] + red[5] + red[6] + red[7];

    const float mu  = s / (float)H;
    const float var = s2 / (float)H - mu * mu;
    const float rs  = rsqrtf(var + 1e-5f);

    bf16x4 hv = *(const bf16x4*)&h[base];
    bf16x4 o;
#pragma unroll
    for (int j = 0; j < 4; j++) {
        float gn = (zf[j] - mu) * rs * ge[t * 4 + j] + be[t * 4 + j];
        gn = gn > 0.f ? gn : 0.f;
        o[j] = f2bf(gn + bf2f(hv[j]));
    }
    *(bf16x4*)&z[base] = o;
}

// ---------------- gate: logits = gh @ Wg2^T + bg2 ; softmax over 8 ----------
__global__ __launch_bounds__(256) void gate2_kernel(
    const ushort* __restrict__ gh,   // [B,256] bf16
    const float* __restrict__ Wg2,   // [8,256]
    const float* __restrict__ bg2,   // [8]
    float* __restrict__ gate)        // [B,8]
{
    const int wv = threadIdx.x >> 6, lane = threadIdx.x & 63;
    const int r = blockIdx.x * 4 + wv;

    bf16x4 v = *(const bf16x4*)&gh[(size_t)r * 256 + lane * 4];
    float gf[4];
#pragma unroll
    for (int j = 0; j < 4; j++) gf[j] = bf2f(v[j]);

    float lg[8];
#pragma unroll
    for (int e = 0; e < 8; e++) {
        const float* w = Wg2 + e * 256 + lane * 4;
        float p = gf[0]*w[0] + gf[1]*w[1] + gf[2]*w[2] + gf[3]*w[3];
#pragma unroll
        for (int off = 32; off; off >>= 1) p += __shfl_xor(p, off);
        lg[e] = p + bg2[e];
    }
    float mx = lg[0];
#pragma unroll
    for (int e = 1; e < 8; e++) mx = fmaxf(mx, lg[e]);
    float ex[8], ssum = 0.f;
#pragma unroll
    for (int e = 0; e < 8; e++) { ex[e] = expf(lg[e] - mx); ssum += ex[e]; }
    const float inv = 1.f / ssum;
    float myex = 0.f;
#pragma unroll
    for (int e = 0; e < 8; e++) myex = (lane == e) ? ex[e] : myex;
    if (lane < 8) gate[(size_t)r * 8 + lane] = myex * inv;
}

// ---------------- gated combine: out (+)= sum_el gate[b,e0+el] * eo[el,b,:] --
__global__ __launch_bounds__(256) void combine_kernel(
    const ushort* __restrict__ eo,   // [eg, B, D] bf16 (acc + b2 already)
    const float* __restrict__ gate,  // [B, 8]
    float* __restrict__ out,         // [B, D]
    int B, int D, int e0, int eg, int init)
{
    int t = blockIdx.x * 256 + threadIdx.x;   // over B*D/4
    int dq = D >> 2;
    int b = t / dq;
    int d = (t - b * dq) * 4;
    if (b >= B) return;

    float4 s = {0.f, 0.f, 0.f, 0.f};
    for (int el = 0; el < eg; el++) {
        const float g = gate[(size_t)b * 8 + e0 + el];
        bf16x4 v = *(const bf16x4*)&eo[((size_t)el * B + b) * D + d];
        s.x += g * bf2f(v.x);
        s.y += g * bf2f(v.y);
        s.z += g * bf2f(v.z);
        s.w += g * bf2f(v.w);
    }
    float4* o = (float4*)&out[(size_t)b * D + d];
    if (init) *o = s;
    else {
        float4 p = *o;
        p.x += s.x; p.y += s.y; p.z += s.z; p.w += s.w;
        *o = p;
    }
}

// ---------------- host ----------------
extern "C" void kernel_launch(void* const* d_in, const int* in_sizes, int n_in,
                              void* d_out, int out_size, void* d_ws, size_t ws_size,
                              hipStream_t stream)
{
    const float* x   = (const float*)d_in[0];
    const float* W0  = (const float*)d_in[1];
    const float* b0  = (const float*)d_in[2];
    const float* W1  = (const float*)d_in[3];
    const float* b1  = (const float*)d_in[4];
    const float* lng = (const float*)d_in[5];
    const float* lnb = (const float*)d_in[6];
    const float* W2  = (const float*)d_in[7];
    const float* b2  = (const float*)d_in[8];
    const float* Wg1 = (const float*)d_in[9];
    const float* bg1 = (const float*)d_in[10];
    const float* Wg2 = (const float*)d_in[11];
    const float* bg2 = (const float*)d_in[12];
    float* out = (float*)d_out;

    const int B = 8192, D = 1024, H = 1024, E = 8, G = 256;

    // fixed workspace
    char* ws = (char*)d_ws;
    ushort* x_bf  = (ushort*)ws;  ws += (size_t)B * D * 2;
    ushort* w0_bf = (ushort*)ws;  ws += (size_t)E * H * D * 2;
    ushort* w1_bf = (ushort*)ws;  ws += (size_t)E * H * H * 2;
    ushort* w2_bf = (ushort*)ws;  ws += (size_t)E * D * H * 2;
    ushort* wg1bf = (ushort*)ws;  ws += (size_t)G * D * 2;
    ushort* gh_bf = (ushort*)ws;  ws += (size_t)B * G * 2;
    float*  gatep = (float*)ws;   ws += (size_t)B * E * 4;

    // expert-group size chosen from remaining ws (EG=1 == round-1 footprint)
    size_t used  = (size_t)(ws - (char*)d_ws);
    size_t avail = (ws_size > used) ? ws_size - used : 0;
    size_t per_eg = (size_t)B * H * 2 * 2;   // h-buf + z-buf per expert
    int EG = 1;
    for (int cand = 8; cand >= 1; cand >>= 1)
        if ((size_t)cand * per_eg <= avail) { EG = cand; break; }

    ushort* hbuf = (ushort*)ws;                           // [EG, B, H]
    ushort* zbuf = (ushort*)(ws + (size_t)EG * B * H * 2); // [EG, B, H]

    auto cvt = [&](const float* src, ushort* dst, size_t n) {
        int n4 = (int)(n / 4);
        int blocks = (n4 + 255) / 256;
        if (blocks > 2048) blocks = 2048;
        cvt_kernel<<<dim3(blocks), dim3(256), 0, stream>>>(src, dst, n4);
    };
    cvt(x,   x_bf,  (size_t)B * D);
    cvt(W0,  w0_bf, (size_t)E * H * D);
    cvt(W1,  w1_bf, (size_t)E * H * H);
    cvt(W2,  w2_bf, (size_t)E * D * H);
    cvt(Wg1, wg1bf, (size_t)G * D);

    // gate hidden: [B,G] = relu(x @ Wg1^T + bg1); then softmax over experts
    gemm_bt<0><<<dim3(B / 128, G / 128, 1), dim3(256), 0, stream>>>(
        x_bf, wg1bf, bg1, gh_bf, B, G, D, 0, 0, 0, 0);
    gate2_kernel<<<dim3(B / 4), dim3(256), 0, stream>>>(gh_bf, Wg2, bg2, gatep);

    for (int e0 = 0; e0 < E; e0 += EG) {
        const int eg = (E - e0 < EG) ? (E - e0) : EG;
        // layer0: h = relu(x @ W0[e]^T + b0[e])   (A shared across z)
        gemm_bt<0><<<dim3(B / 128, H / 128, eg), dim3(256), 0, stream>>>(
            x_bf, w0_bf + (size_t)e0 * H * D, b0 + (size_t)e0 * H, hbuf,
            B, H, D, 0, (long)H * D, H, (long)B * H);
        // layer1: z = h @ W1[e]^T + b1[e]
        gemm_bt<1><<<dim3(B / 128, H / 128, eg), dim3(256), 0, stream>>>(
            hbuf, w1_bf + (size_t)e0 * H * H, b1 + (size_t)e0 * H, zbuf,
            B, H, H, (long)B * H, (long)H * H, H, (long)B * H);
        // LN -> relu -> +h (in place: zbuf becomes hp)
        ln_kernel<<<dim3(B, eg), dim3(256), 0, stream>>>(
            zbuf, hbuf, lng + (size_t)e0 * H, lnb + (size_t)e0 * H, B, H);
        // layer2: eo = hp @ W2[e]^T + b2[e]  (into hbuf, h is dead)
        gemm_bt<1><<<dim3(B / 128, D / 128, eg), dim3(256), 0, stream>>>(
            zbuf, w2_bf + (size_t)e0 * D * H, b2 + (size_t)e0 * D, hbuf,
            B, D, H, (long)B * H, (long)D * H, D, (long)B * D);
        // gated combine into out
        combine_kernel<<<dim3((B * (D / 4) + 255) / 256), dim3(256), 0, stream>>>(
            hbuf, gatep, out, B, D, e0, eg, (e0 == 0) ? 1 : 0);
    }
}